// Round 1
// baseline (213.364 us; speedup 1.0000x reference)
//
#include <hip/hip_runtime.h>
#include <math.h>

// exp2 via native v_exp_f32 when the builtin exists; fallback to __expf.
#if defined(__has_builtin)
#  if __has_builtin(__builtin_amdgcn_exp2f)
#    define EXP2F(x) __builtin_amdgcn_exp2f(x)
#  endif
#endif
#ifndef EXP2F
#  define EXP2F(x) __expf(0.69314718055994530942f * (x))
#endif

// One layer of the OR-gate net:
//   aw = leaky_clamp(W, 0, 1, 0.1)
//   z[b,o,i] = h[b,i] * aw[o,i]
//   out[b,o] = sum_i z * softmax_i(tau * z)      (no max-subtraction needed:
//              tau*z <= ~36 -> exp2 args well within fp32 range)
//   hout = 1 - out
//
// Folding: arg = c2*z with c2 = tau*log2(e); e = exp2(arg);
//   sum z*e = (sum arg*e)/c2  ->  out = t/(s*c2).
//
// Mapping: wave = BB(8) batch rows x OB(4) outputs, lanes = 64 consecutive i.
// Block = 4 waves sharing the same o-tile (W rows reused via L1),
// covering 32 batch rows. grid.x = (OUT/OB) * (128/(8*4)) = OUT.
template <int IN, int OUT, bool FIRST>
__launch_bounds__(256, 2)
__global__ void or_layer(const float* __restrict__ hin,
                         const float* __restrict__ W,
                         const float* __restrict__ tau_ptr,
                         float* __restrict__ hout,
                         float tau_floor) {
  constexpr int BB = 8;  // batch rows per wave
  constexpr int OB = 4;  // outputs per wave
  const int lane = threadIdx.x & 63;
  const int wid  = threadIdx.x >> 6;
  constexpr int nOT = OUT / OB;
  const int ot = blockIdx.x % nOT;
  const int bs = blockIdx.x / nOT;       // 0..3
  const int b0 = (bs * 4 + wid) * BB;    // 0..120
  const int o0 = ot * OB;

  const float ta  = tau_ptr[0];
  const float tau = tau_floor + (ta >= 0.0f ? ta : 0.05f * ta);
  const float c2  = tau * 1.44269504088896340736f;  // tau * log2(e)

  float s[BB][OB];
  float t[BB][OB];
#pragma unroll
  for (int r = 0; r < BB; ++r)
#pragma unroll
    for (int c = 0; c < OB; ++c) { s[r][c] = 0.0f; t[r][c] = 0.0f; }

#pragma unroll 1
  for (int ic = 0; ic < IN / 64; ++ic) {
    const int i = ic * 64 + lane;

    float h[BB];
    if (FIRST) {
      // hin is x: (128, IN/2); h = concat(x, 1 - x). The i<IN/2 test is
      // wave-uniform (chunk-aligned), so no real divergence.
#pragma unroll
      for (int r = 0; r < BB; ++r) {
        if (i < IN / 2) h[r] = hin[(b0 + r) * (IN / 2) + i];
        else            h[r] = 1.0f - hin[(b0 + r) * (IN / 2) + (i - IN / 2)];
      }
    } else {
#pragma unroll
      for (int r = 0; r < BB; ++r) h[r] = hin[(b0 + r) * IN + i];
    }

    float cw[OB];
#pragma unroll
    for (int c = 0; c < OB; ++c) {
      const float w  = W[(o0 + c) * IN + i];
      const float aw = (w < 0.0f) ? 0.1f * w
                     : (w > 1.0f) ? fmaf(0.1f, w - 1.0f, 1.0f)
                     : w;
      cw[c] = c2 * aw;
    }

#pragma unroll
    for (int r = 0; r < BB; ++r)
#pragma unroll
      for (int c = 0; c < OB; ++c) {
        const float arg = cw[c] * h[r];
        const float e   = EXP2F(arg);
        s[r][c] += e;
        t[r][c]  = fmaf(arg, e, t[r][c]);
      }
  }

  // Butterfly reduce over the 64 lanes (partials over i live one-per-lane).
#pragma unroll
  for (int m = 1; m < 64; m <<= 1) {
#pragma unroll
    for (int r = 0; r < BB; ++r)
#pragma unroll
      for (int c = 0; c < OB; ++c) {
        s[r][c] += __shfl_xor(s[r][c], m, 64);
        t[r][c] += __shfl_xor(t[r][c], m, 64);
      }
  }

  if (lane == 0) {
    const float inv_c2 = 1.0f / c2;
#pragma unroll
    for (int r = 0; r < BB; ++r)
#pragma unroll
      for (int c = 0; c < OB; ++c) {
        const float out = t[r][c] / s[r][c] * inv_c2;  // sum(z e)/sum(e)
        hout[(b0 + r) * OUT + (o0 + c)] = 1.0f - out;
      }
  }
}

extern "C" void kernel_launch(void* const* d_in, const int* in_sizes, int n_in,
                              void* d_out, int out_size, void* d_ws, size_t ws_size,
                              hipStream_t stream) {
  // setup_inputs() dict order: x, W0, tau0, W1, tau1, W2, tau2, W3, tau3
  const float* x    = (const float*)d_in[0];
  const float* W0   = (const float*)d_in[1];
  const float* tau0 = (const float*)d_in[2];
  const float* W1   = (const float*)d_in[3];
  const float* tau1 = (const float*)d_in[4];
  const float* W2   = (const float*)d_in[5];
  const float* tau2 = (const float*)d_in[6];
  const float* W3   = (const float*)d_in[7];
  const float* tau3 = (const float*)d_in[8];

  float* h1  = (float*)d_ws;        // 128*1024 floats
  float* h2  = h1 + 128 * 1024;     // 128*512
  float* h3  = h2 + 128 * 512;      // 128*256
  float* out = (float*)d_out;       // 128*128

  const double LOGR = 2.9444389791664403;  // log(0.95) - log(0.05) = log(19)
  const float tf1024 = (float)(log(1023.0) + LOGR);
  const float tf512  = (float)(log(511.0)  + LOGR);
  const float tf256  = (float)(log(255.0)  + LOGR);

  or_layer<1024, 1024, true ><<<1024, 256, 0, stream>>>(x,  W0, tau0, h1,  tf1024);
  or_layer<1024,  512, false><<< 512, 256, 0, stream>>>(h1, W1, tau1, h2,  tf1024);
  or_layer< 512,  256, false><<< 256, 256, 0, stream>>>(h2, W2, tau2, h3,  tf512);
  or_layer< 256,  128, false><<< 128, 256, 0, stream>>>(h3, W3, tau3, out, tf256);
}

// Round 2
// 130.811 us; speedup vs baseline: 1.6311x; 1.6311x over previous
//
#include <hip/hip_runtime.h>
#include <math.h>

// exp2 via native v_exp_f32 when the builtin exists; fallback to __expf.
#if defined(__has_builtin)
#  if __has_builtin(__builtin_amdgcn_exp2f)
#    define EXP2F(x) __builtin_amdgcn_exp2f(x)
#  endif
#endif
#ifndef EXP2F
#  define EXP2F(x) __expf(0.69314718055994530942f * (x))
#endif

// One layer of the OR-gate net:
//   aw = leaky_clamp(W, 0, 1, 0.1)
//   z[b,o,i] = h[b,i] * aw[o,i]
//   out[b,o] = sum_i z * softmax_i(tau * z)   (tau*z <= ~36: no max-subtract needed)
//   hout = 1 - out
//
// Folding: arg = c2*z, c2 = tau*log2(e); e = exp2(arg); sum z*e = (sum arg*e)/c2.
//
// Mapping (R1): wave = BB(4) batch rows x OB(4) outputs; 64 lanes x float4 = 256
// consecutive i per iteration (dwordx4 coalesced). Block = 4 waves (16 batch
// rows) sharing one o-tile. grid = (OUT/4) * (128/16) blocks -> >= 256 blocks
// even for the last layer. No launch-bounds occupancy cap; VGPR ~110 -> 4-5
// waves/SIMD for latency hiding (R0 was latency-bound at 24% occupancy).
template <int IN, int OUT, bool FIRST>
__launch_bounds__(256)
__global__ void or_layer(const float* __restrict__ hin,
                         const float* __restrict__ W,
                         const float* __restrict__ tau_ptr,
                         float* __restrict__ hout,
                         float tau_floor) {
  constexpr int BB = 4;   // batch rows per wave
  constexpr int OB = 4;   // outputs per wave
  constexpr int NIT = IN / 256;
  constexpr int nOT = OUT / OB;

  const int lane = threadIdx.x & 63;
  const int wid  = threadIdx.x >> 6;
  const int ot = blockIdx.x % nOT;
  const int bs = blockIdx.x / nOT;          // 0..7
  const int b0 = (bs * 4 + wid) * BB;       // 0..124
  const int o0 = ot * OB;

  const float ta  = tau_ptr[0];
  const float tau = tau_floor + (ta >= 0.0f ? ta : 0.05f * ta);
  const float c2  = tau * 1.44269504088896340736f;  // tau * log2(e)

  const float4* __restrict__ Wv = (const float4*)W;
  const float4* __restrict__ Hv = (const float4*)hin;

  float s[BB][OB], t[BB][OB];
#pragma unroll
  for (int r = 0; r < BB; ++r)
#pragma unroll
    for (int c = 0; c < OB; ++c) { s[r][c] = 0.0f; t[r][c] = 0.0f; }

#pragma unroll 2
  for (int ic = 0; ic < NIT; ++ic) {
    const int i4 = ic * 64 + lane;          // float4 index within [0, IN/4)

    float hc[BB][4];
    if (FIRST) {
      // hin is x: (128, IN/2); h = concat(x, 1-x). Branch is wave-uniform
      // (256-element chunks align with the IN/2 boundary).
      constexpr int HALF4 = IN / 8;         // float4s per x row
      if (i4 < HALF4) {
#pragma unroll
        for (int r = 0; r < BB; ++r) {
          float4 v = Hv[(b0 + r) * HALF4 + i4];
          hc[r][0] = v.x; hc[r][1] = v.y; hc[r][2] = v.z; hc[r][3] = v.w;
        }
      } else {
#pragma unroll
        for (int r = 0; r < BB; ++r) {
          float4 v = Hv[(b0 + r) * HALF4 + (i4 - HALF4)];
          hc[r][0] = 1.0f - v.x; hc[r][1] = 1.0f - v.y;
          hc[r][2] = 1.0f - v.z; hc[r][3] = 1.0f - v.w;
        }
      }
    } else {
#pragma unroll
      for (int r = 0; r < BB; ++r) {
        float4 v = Hv[(b0 + r) * (IN / 4) + i4];
        hc[r][0] = v.x; hc[r][1] = v.y; hc[r][2] = v.z; hc[r][3] = v.w;
      }
    }

    float cw[OB][4];
#pragma unroll
    for (int c = 0; c < OB; ++c) {
      float4 v = Wv[(o0 + c) * (IN / 4) + i4];
      float wj[4] = {v.x, v.y, v.z, v.w};
#pragma unroll
      for (int j = 0; j < 4; ++j) {
        const float m  = fminf(fmaxf(wj[j], 0.0f), 1.0f);   // med3 clamp
        const float aw = fmaf(0.1f, wj[j] - m, m);          // leaky outside
        cw[c][j] = c2 * aw;
      }
    }

#pragma unroll
    for (int r = 0; r < BB; ++r)
#pragma unroll
      for (int c = 0; c < OB; ++c)
#pragma unroll
        for (int j = 0; j < 4; ++j) {
          const float arg = cw[c][j] * hc[r][j];
          const float e   = EXP2F(arg);
          s[r][c] += e;
          t[r][c]  = fmaf(arg, e, t[r][c]);
        }
  }

  // Butterfly reduce the per-lane partials over the 64 lanes.
#pragma unroll
  for (int m = 1; m < 64; m <<= 1) {
#pragma unroll
    for (int r = 0; r < BB; ++r)
#pragma unroll
      for (int c = 0; c < OB; ++c) {
        s[r][c] += __shfl_xor(s[r][c], m, 64);
        t[r][c] += __shfl_xor(t[r][c], m, 64);
      }
  }

  if (lane == 0) {
    const float inv_c2 = 1.0f / c2;
#pragma unroll
    for (int r = 0; r < BB; ++r)
#pragma unroll
      for (int c = 0; c < OB; ++c) {
        const float out = t[r][c] / s[r][c] * inv_c2;  // sum(z e)/sum(e)
        hout[(b0 + r) * OUT + (o0 + c)] = 1.0f - out;
      }
  }
}

extern "C" void kernel_launch(void* const* d_in, const int* in_sizes, int n_in,
                              void* d_out, int out_size, void* d_ws, size_t ws_size,
                              hipStream_t stream) {
  // setup_inputs() dict order: x, W0, tau0, W1, tau1, W2, tau2, W3, tau3
  const float* x    = (const float*)d_in[0];
  const float* W0   = (const float*)d_in[1];
  const float* tau0 = (const float*)d_in[2];
  const float* W1   = (const float*)d_in[3];
  const float* tau1 = (const float*)d_in[4];
  const float* W2   = (const float*)d_in[5];
  const float* tau2 = (const float*)d_in[6];
  const float* W3   = (const float*)d_in[7];
  const float* tau3 = (const float*)d_in[8];

  float* h1  = (float*)d_ws;        // 128*1024 floats
  float* h2  = h1 + 128 * 1024;     // 128*512
  float* h3  = h2 + 128 * 512;      // 128*256
  float* out = (float*)d_out;       // 128*128

  const double LOGR = 2.9444389791664403;  // log(0.95) - log(0.05) = log(19)
  const float tf1024 = (float)(log(1023.0) + LOGR);
  const float tf512  = (float)(log(511.0)  + LOGR);
  const float tf256  = (float)(log(255.0)  + LOGR);

  or_layer<1024, 1024, true ><<<2048, 256, 0, stream>>>(x,  W0, tau0, h1,  tf1024);
  or_layer<1024,  512, false><<<1024, 256, 0, stream>>>(h1, W1, tau1, h2,  tf1024);
  or_layer< 512,  256, false><<< 512, 256, 0, stream>>>(h2, W2, tau2, h3,  tf512);
  or_layer< 256,  128, false><<< 256, 256, 0, stream>>>(h3, W3, tau3, out, tf256);
}

// Round 3
// 124.650 us; speedup vs baseline: 1.7117x; 1.0494x over previous
//
#include <hip/hip_runtime.h>
#include <math.h>

// exp2 via native v_exp_f32 when the builtin exists; fallback to __expf.
#if defined(__has_builtin)
#  if __has_builtin(__builtin_amdgcn_exp2f)
#    define EXP2F(x) __builtin_amdgcn_exp2f(x)
#  endif
#endif
#ifndef EXP2F
#  define EXP2F(x) __expf(0.69314718055994530942f * (x))
#endif

// One layer of the OR-gate net:
//   aw = leaky_clamp(W, 0, 1, 0.1)
//   z[b,o,i] = h[b,i] * aw[o,i]
//   out[b,o] = sum_i z * softmax_i(tau * z)   (tau*z <= ~36: no max-subtract needed)
//   hout = 1 - out
//
// Folding: arg = c2*z, c2 = tau*log2(e); e = exp2(arg); sum z*e = (sum arg*e)/c2.
//
// R2 mapping (this round): 2-D lane split. lane = il(16 lanes over i) x og(4
// o-groups). Each group owns OBB=2 outputs -> 8 outputs/wave; BB batch rows
// per wave (template: 8/8/4/2 per layer to keep grid >= 256 blocks).
// Per iter the wave covers 64 i (il * float4). vs R1's 64-lane i-split this
// gives 4x the K-loop iterations (NIT: L0 4->16) and a 4-step (not 6-step)
// shuffle tail over 32 accumulators -- the R1 profile was tail/latency bound,
// not VALU bound (VALUBusy 26%).
template <int IN, int OUT, int BB, bool FIRST>
__launch_bounds__(256)
__global__ void or_layer(const float* __restrict__ hin,
                         const float* __restrict__ W,
                         const float* __restrict__ tau_ptr,
                         float* __restrict__ hout,
                         float tau_floor) {
  constexpr int OBB = 2;                 // outputs per 16-lane group
  constexpr int NIT = IN / 64;           // 16 lanes x float4 per iter
  constexpr int nOT = OUT / 32;          // 4 waves x 8 outputs per block

  const int lane = threadIdx.x & 63;
  const int wid  = threadIdx.x >> 6;
  const int il   = lane & 15;            // i-lane within group
  const int og   = lane >> 4;            // o-group 0..3

  const int ot = blockIdx.x % nOT;
  const int bt = blockIdx.x / nOT;
  const int b0 = bt * BB;
  const int o0 = ot * 32 + wid * 8 + og * OBB;   // this lane's first output

  const float ta  = tau_ptr[0];
  const float tau = tau_floor + (ta >= 0.0f ? ta : 0.05f * ta);
  const float c2  = tau * 1.44269504088896340736f;  // tau * log2(e)

  const float4* __restrict__ Wv = (const float4*)W;
  const float4* __restrict__ Hv = (const float4*)hin;

  float s[BB][OBB], t[BB][OBB];
#pragma unroll
  for (int r = 0; r < BB; ++r)
#pragma unroll
    for (int c = 0; c < OBB; ++c) { s[r][c] = 0.0f; t[r][c] = 0.0f; }

#pragma unroll 2
  for (int ic = 0; ic < NIT; ++ic) {
    const int i4 = ic * 16 + il;         // float4 index within [0, IN/4)

    float hc[BB][4];
    if (FIRST) {
      // hin is x: (128, IN/2); h = concat(x, 1-x). 64-float chunks align with
      // the IN/2 boundary, so the branch is uniform across each iteration.
      constexpr int HALF4 = IN / 8;      // float4s per x row
      if (i4 < HALF4) {
#pragma unroll
        for (int r = 0; r < BB; ++r) {
          float4 v = Hv[(b0 + r) * HALF4 + i4];
          hc[r][0] = v.x; hc[r][1] = v.y; hc[r][2] = v.z; hc[r][3] = v.w;
        }
      } else {
#pragma unroll
        for (int r = 0; r < BB; ++r) {
          float4 v = Hv[(b0 + r) * HALF4 + (i4 - HALF4)];
          hc[r][0] = 1.0f - v.x; hc[r][1] = 1.0f - v.y;
          hc[r][2] = 1.0f - v.z; hc[r][3] = 1.0f - v.w;
        }
      }
    } else {
#pragma unroll
      for (int r = 0; r < BB; ++r) {
        float4 v = Hv[(b0 + r) * (IN / 4) + i4];
        hc[r][0] = v.x; hc[r][1] = v.y; hc[r][2] = v.z; hc[r][3] = v.w;
      }
    }

    float cw[OBB][4];
#pragma unroll
    for (int c = 0; c < OBB; ++c) {
      float4 v = Wv[(o0 + c) * (IN / 4) + i4];
      float wj[4] = {v.x, v.y, v.z, v.w};
#pragma unroll
      for (int j = 0; j < 4; ++j) {
        const float m  = fminf(fmaxf(wj[j], 0.0f), 1.0f);   // med3 clamp
        const float aw = fmaf(0.1f, wj[j] - m, m);          // leaky outside
        cw[c][j] = c2 * aw;
      }
    }

#pragma unroll
    for (int r = 0; r < BB; ++r)
#pragma unroll
      for (int c = 0; c < OBB; ++c)
#pragma unroll
        for (int j = 0; j < 4; ++j) {
          const float arg = cw[c][j] * hc[r][j];
          const float e   = EXP2F(arg);
          s[r][c] += e;
          t[r][c]  = fmaf(arg, e, t[r][c]);
        }
  }

  // Reduce partials across the 16 i-lanes of each group (xor masks 1..8 stay
  // within the group).
#pragma unroll
  for (int m = 1; m < 16; m <<= 1) {
#pragma unroll
    for (int r = 0; r < BB; ++r)
#pragma unroll
      for (int c = 0; c < OBB; ++c) {
        s[r][c] += __shfl_xor(s[r][c], m, 64);
        t[r][c] += __shfl_xor(t[r][c], m, 64);
      }
  }

  if (il == 0) {
    const float inv_c2 = 1.0f / c2;
#pragma unroll
    for (int r = 0; r < BB; ++r)
#pragma unroll
      for (int c = 0; c < OBB; ++c) {
        const float out = t[r][c] / s[r][c] * inv_c2;  // sum(z e)/sum(e)
        hout[(b0 + r) * OUT + (o0 + c)] = 1.0f - out;
      }
  }
}

extern "C" void kernel_launch(void* const* d_in, const int* in_sizes, int n_in,
                              void* d_out, int out_size, void* d_ws, size_t ws_size,
                              hipStream_t stream) {
  // setup_inputs() dict order: x, W0, tau0, W1, tau1, W2, tau2, W3, tau3
  const float* x    = (const float*)d_in[0];
  const float* W0   = (const float*)d_in[1];
  const float* tau0 = (const float*)d_in[2];
  const float* W1   = (const float*)d_in[3];
  const float* tau1 = (const float*)d_in[4];
  const float* W2   = (const float*)d_in[5];
  const float* tau2 = (const float*)d_in[6];
  const float* W3   = (const float*)d_in[7];
  const float* tau3 = (const float*)d_in[8];

  float* h1  = (float*)d_ws;        // 128*1024 floats
  float* h2  = h1 + 128 * 1024;     // 128*512
  float* h3  = h2 + 128 * 512;      // 128*256
  float* out = (float*)d_out;       // 128*128

  const double LOGR = 2.9444389791664403;  // log(0.95) - log(0.05) = log(19)
  const float tf1024 = (float)(log(1023.0) + LOGR);
  const float tf512  = (float)(log(511.0)  + LOGR);
  const float tf256  = (float)(log(255.0)  + LOGR);

  // grid = (OUT/32) * (128/BB); BB tuned per layer so every layer fills the
  // 256 CUs: L0 512, L1 256, L2 256, L3 256 blocks.
  or_layer<1024, 1024, 8, true ><<<32 * 16, 256, 0, stream>>>(x,  W0, tau0, h1,  tf1024);
  or_layer<1024,  512, 8, false><<<16 * 16, 256, 0, stream>>>(h1, W1, tau1, h2,  tf1024);
  or_layer< 512,  256, 4, false><<< 8 * 32, 256, 0, stream>>>(h2, W2, tau2, h3,  tf512);
  or_layer< 256,  128, 2, false><<< 4 * 64, 256, 0, stream>>>(h3, W3, tau3, out, tf256);
}

// Round 4
// 124.598 us; speedup vs baseline: 1.7124x; 1.0004x over previous
//
#include <hip/hip_runtime.h>
#include <math.h>

// HW exp2 (v_exp_f32) when available.
#if defined(__has_builtin)
#  if __has_builtin(__builtin_amdgcn_exp2f)
#    define EXP2F(x) __builtin_amdgcn_exp2f(x)
#  endif
#endif
#ifndef EXP2F
#  define EXP2F(x) __expf(0.69314718055994530942f * (x))
#endif

// Full-rate-VALU exp2: magic-constant round-to-nearest, deg-3 Taylor on
// f in [-0.5,0.5] (rel err <= 6e-4), exponent rebuilt via (y_int<<23)+p_int.
// 0x4B400000<<23 == 0 mod 2^32, so the shift leaves exactly n<<23.
// Valid for |n| < 512; here arg in [-8, 37]. ~7 full-rate ops, no trans pipe.
__device__ __forceinline__ float fast_exp2(float x) {
  const float M = 12582912.0f;             // 1.5 * 2^23
  const float y = x + M;                   // RNE(x) encoded in mantissa
  const float n = y - M;
  const float f = x - n;                   // [-0.5, 0.5]
  float p = fmaf(f, 0.055504109f, 0.24022651f);
  p = fmaf(f, p, 0.69314718f);
  p = fmaf(f, p, 1.0f);                    // 2^f
  const int r = (__float_as_int(y) << 23) + __float_as_int(p);
  return __int_as_float(r);
}

// One layer of the OR-gate net:
//   aw = leaky_clamp(W, 0, 1, 0.1); z = h*aw
//   out[b,o] = sum_i z * softmax_i(tau*z); hout = 1 - out
// Folding: arg = c2*z, c2 = tau*log2(e); sum z*e = (sum arg*e)/c2.
//
// R3 evidence: runtime ∝ z-count, insensitive to occupancy, VALUBusy ~26%
// -> transcendental pipe saturated (v_exp_f32 ~16 lanes/cy/CU). This round:
// hybrid exp — elements j=0,2 on the trans pipe, j=1,3 via fast_exp2 on the
// full-rate pipe, balancing the two pipes (~21 µs full-rate vs ~11 µs trans
// at 100% issue).
template <int IN, int OUT, int BB, bool FIRST>
__launch_bounds__(256)
__global__ void or_layer(const float* __restrict__ hin,
                         const float* __restrict__ W,
                         const float* __restrict__ tau_ptr,
                         float* __restrict__ hout,
                         float tau_floor) {
  constexpr int OBB = 2;                 // outputs per 16-lane group
  constexpr int NIT = IN / 64;           // 16 lanes x float4 per iter
  constexpr int nOT = OUT / 32;          // 4 waves x 8 outputs per block

  const int lane = threadIdx.x & 63;
  const int wid  = threadIdx.x >> 6;
  const int il   = lane & 15;            // i-lane within group
  const int og   = lane >> 4;            // o-group 0..3

  const int ot = blockIdx.x % nOT;
  const int bt = blockIdx.x / nOT;
  const int b0 = bt * BB;
  const int o0 = ot * 32 + wid * 8 + og * OBB;

  const float ta  = tau_ptr[0];
  const float tau = tau_floor + (ta >= 0.0f ? ta : 0.05f * ta);
  const float c2  = tau * 1.44269504088896340736f;  // tau * log2(e)

  const float4* __restrict__ Wv = (const float4*)W;
  const float4* __restrict__ Hv = (const float4*)hin;

  float s[BB][OBB], t[BB][OBB];
#pragma unroll
  for (int r = 0; r < BB; ++r)
#pragma unroll
    for (int c = 0; c < OBB; ++c) { s[r][c] = 0.0f; t[r][c] = 0.0f; }

#pragma unroll 2
  for (int ic = 0; ic < NIT; ++ic) {
    const int i4 = ic * 16 + il;         // float4 index within [0, IN/4)

    float hc[BB][4];
    if (FIRST) {
      // hin is x: (128, IN/2); h = concat(x, 1-x). 64-float chunks align
      // with the IN/2 boundary -> branch uniform per iteration.
      constexpr int HALF4 = IN / 8;
      if (i4 < HALF4) {
#pragma unroll
        for (int r = 0; r < BB; ++r) {
          float4 v = Hv[(b0 + r) * HALF4 + i4];
          hc[r][0] = v.x; hc[r][1] = v.y; hc[r][2] = v.z; hc[r][3] = v.w;
        }
      } else {
#pragma unroll
        for (int r = 0; r < BB; ++r) {
          float4 v = Hv[(b0 + r) * HALF4 + (i4 - HALF4)];
          hc[r][0] = 1.0f - v.x; hc[r][1] = 1.0f - v.y;
          hc[r][2] = 1.0f - v.z; hc[r][3] = 1.0f - v.w;
        }
      }
    } else {
#pragma unroll
      for (int r = 0; r < BB; ++r) {
        float4 v = Hv[(b0 + r) * (IN / 4) + i4];
        hc[r][0] = v.x; hc[r][1] = v.y; hc[r][2] = v.z; hc[r][3] = v.w;
      }
    }

    float cw[OBB][4];
#pragma unroll
    for (int c = 0; c < OBB; ++c) {
      float4 v = Wv[(o0 + c) * (IN / 4) + i4];
      float wj[4] = {v.x, v.y, v.z, v.w};
#pragma unroll
      for (int j = 0; j < 4; ++j) {
        const float m  = fminf(fmaxf(wj[j], 0.0f), 1.0f);   // med3 clamp
        const float aw = fmaf(0.1f, wj[j] - m, m);          // leaky outside
        cw[c][j] = c2 * aw;
      }
    }

#pragma unroll
    for (int r = 0; r < BB; ++r)
#pragma unroll
      for (int c = 0; c < OBB; ++c)
#pragma unroll
        for (int j = 0; j < 4; ++j) {
          const float arg = cw[c][j] * hc[r][j];
          // Hybrid: even j on the trans pipe, odd j on the full-rate pipe.
          const float e = (j & 1) ? fast_exp2(arg) : EXP2F(arg);
          s[r][c] += e;
          t[r][c]  = fmaf(arg, e, t[r][c]);
        }
  }

  // Reduce partials across the 16 i-lanes of each group.
#pragma unroll
  for (int m = 1; m < 16; m <<= 1) {
#pragma unroll
    for (int r = 0; r < BB; ++r)
#pragma unroll
      for (int c = 0; c < OBB; ++c) {
        s[r][c] += __shfl_xor(s[r][c], m, 64);
        t[r][c] += __shfl_xor(t[r][c], m, 64);
      }
  }

  if (il == 0) {
    const float inv_c2 = 1.0f / c2;
#pragma unroll
    for (int r = 0; r < BB; ++r)
#pragma unroll
      for (int c = 0; c < OBB; ++c) {
        const float out = t[r][c] / s[r][c] * inv_c2;  // sum(z e)/sum(e)
        hout[(b0 + r) * OUT + (o0 + c)] = 1.0f - out;
      }
  }
}

extern "C" void kernel_launch(void* const* d_in, const int* in_sizes, int n_in,
                              void* d_out, int out_size, void* d_ws, size_t ws_size,
                              hipStream_t stream) {
  // setup_inputs() dict order: x, W0, tau0, W1, tau1, W2, tau2, W3, tau3
  const float* x    = (const float*)d_in[0];
  const float* W0   = (const float*)d_in[1];
  const float* tau0 = (const float*)d_in[2];
  const float* W1   = (const float*)d_in[3];
  const float* tau1 = (const float*)d_in[4];
  const float* W2   = (const float*)d_in[5];
  const float* tau2 = (const float*)d_in[6];
  const float* W3   = (const float*)d_in[7];
  const float* tau3 = (const float*)d_in[8];

  float* h1  = (float*)d_ws;        // 128*1024 floats
  float* h2  = h1 + 128 * 1024;     // 128*512
  float* h3  = h2 + 128 * 512;      // 128*256
  float* out = (float*)d_out;       // 128*128

  const double LOGR = 2.9444389791664403;  // log(0.95) - log(0.05) = log(19)
  const float tf1024 = (float)(log(1023.0) + LOGR);
  const float tf512  = (float)(log(511.0)  + LOGR);
  const float tf256  = (float)(log(255.0)  + LOGR);

  // grid = (OUT/32) * (128/BB): 1024 / 512 / 512 / 512 blocks.
  or_layer<1024, 1024, 4, true ><<<1024, 256, 0, stream>>>(x,  W0, tau0, h1,  tf1024);
  or_layer<1024,  512, 4, false><<< 512, 256, 0, stream>>>(h1, W1, tau1, h2,  tf1024);
  or_layer< 512,  256, 2, false><<< 512, 256, 0, stream>>>(h2, W2, tau2, h3,  tf512);
  or_layer< 256,  128, 1, false><<< 512, 256, 0, stream>>>(h3, W3, tau3, out, tf256);
}